// Round 2
// baseline (1782.335 us; speedup 1.0000x reference)
//
#include <hip/hip_runtime.h>
#include <hip/hip_bf16.h>
#include <cstdint>

#define T_TOK 16384
#define DDIM 1024
#define HDIM 4096
#define RHDIM 1024
#define NEXP 16
#define CHUNK_T 8192

typedef unsigned short u16;
typedef __attribute__((ext_vector_type(4))) float f32x4;
typedef __attribute__((ext_vector_type(8))) __bf16 bf16x8;

__device__ __forceinline__ u16 f2bf(float f) {
  uint32_t u = __builtin_bit_cast(uint32_t, f);
  u += 0x7FFFu + ((u >> 16) & 1u);
  return (u16)(u >> 16);
}

__device__ __forceinline__ void gload_lds16(const void* g, void* l) {
  __builtin_amdgcn_global_load_lds(
      (const __attribute__((address_space(1))) void*)g,
      (__attribute__((address_space(3))) void*)l, 16, 0, 0);
}

// ---------------- diagnostics ----------------

__global__ void ws_diag_kernel(float* __restrict__ out, float wssz) {
  if (threadIdx.x == 0 && blockIdx.x == 0) out[0] = wssz;
}

// ---------------- conversion kernels ----------------

__global__ void cvt_bf16_kernel(const float* __restrict__ in, u16* __restrict__ out, int n4) {
  for (int i = blockIdx.x * blockDim.x + threadIdx.x; i < n4; i += gridDim.x * blockDim.x) {
    float4 v = ((const float4*)in)[i];
    ushort4 o;
    o.x = f2bf(v.x); o.y = f2bf(v.y); o.z = f2bf(v.z); o.w = f2bf(v.w);
    ((ushort4*)out)[i] = o;
  }
}

// in: fp32 [R,C] (batch blockIdx.z), out: bf16 [C,R]
__global__ void transpose_cvt(const float* __restrict__ in, u16* __restrict__ out, int R, int C) {
  __shared__ float tile[32][33];
  const size_t bo = (size_t)blockIdx.z * R * C;
  in += bo; out += bo;
  const int c0 = blockIdx.x * 32, r0 = blockIdx.y * 32;
  const int tx = threadIdx.x, ty = threadIdx.y;  // 32 x 8
#pragma unroll
  for (int i = 0; i < 4; i++)
    tile[ty + 8 * i][tx] = in[(size_t)(r0 + ty + 8 * i) * C + c0 + tx];
  __syncthreads();
#pragma unroll
  for (int i = 0; i < 4; i++)
    out[(size_t)(c0 + ty + 8 * i) * R + r0 + tx] = f2bf(tile[tx][ty + 8 * i]);
}

// ---------------- routing ----------------

__global__ void router_kernel(const float* __restrict__ x, const float* __restrict__ rw,
                              const float* __restrict__ bias, int* __restrict__ top_idx,
                              float* __restrict__ top_gate, int* __restrict__ counts) {
  const int t = blockIdx.x;
  const int lane = threadIdx.x;  // 64
  const float* xt = x + (size_t)t * DDIM;
  float acc[NEXP];
#pragma unroll
  for (int e = 0; e < NEXP; e++) acc[e] = 0.f;
  for (int d = lane; d < DDIM; d += 64) {
    float xv = xt[d];
    const float4* w4 = (const float4*)(rw + (size_t)d * NEXP);
    float4 a = w4[0], b = w4[1], c = w4[2], dd = w4[3];
    acc[0] += xv * a.x;  acc[1] += xv * a.y;  acc[2]  += xv * a.z;  acc[3]  += xv * a.w;
    acc[4] += xv * b.x;  acc[5] += xv * b.y;  acc[6]  += xv * b.z;  acc[7]  += xv * b.w;
    acc[8] += xv * c.x;  acc[9] += xv * c.y;  acc[10] += xv * c.z;  acc[11] += xv * c.w;
    acc[12] += xv * dd.x; acc[13] += xv * dd.y; acc[14] += xv * dd.z; acc[15] += xv * dd.w;
  }
#pragma unroll
  for (int e = 0; e < NEXP; e++) {
    float v = acc[e];
    v += __shfl_xor(v, 32); v += __shfl_xor(v, 16); v += __shfl_xor(v, 8);
    v += __shfl_xor(v, 4);  v += __shfl_xor(v, 2);  v += __shfl_xor(v, 1);
    acc[e] = v;
  }
  if (lane == 0) {
    float sc[NEXP], sel[NEXP];
#pragma unroll
    for (int e = 0; e < NEXP; e++) {
      sc[e] = 1.f / (1.f + expf(-acc[e]));
      sel[e] = sc[e] + bias[e];
    }
    int i1 = 0; float m1 = sel[0];
    for (int e = 1; e < NEXP; e++) if (sel[e] > m1) { m1 = sel[e]; i1 = e; }
    int i2 = -1; float m2 = -1e30f;
    for (int e = 0; e < NEXP; e++) if (e != i1 && sel[e] > m2) { m2 = sel[e]; i2 = e; }
    top_idx[t * 2] = i1; top_idx[t * 2 + 1] = i2;
    top_gate[t * 2] = sc[i1]; top_gate[t * 2 + 1] = sc[i2];
    atomicAdd(&counts[i1], 1);
    atomicAdd(&counts[i2], 1);
  }
}

__global__ void offsets_kernel(const int* __restrict__ counts, int* __restrict__ offpad) {
  if (threadIdx.x == 0 && blockIdx.x == 0) {
    int o = 0;
    for (int e = 0; e < NEXP; e++) { offpad[e] = o; o += (counts[e] + 127) & ~127; }
  }
}

__global__ void fill_kernel(const int* __restrict__ top_idx, const float* __restrict__ top_gate,
                            const int* __restrict__ offpad, int* __restrict__ cursor,
                            int* __restrict__ list_tok, float* __restrict__ list_gate) {
  int t = blockIdx.x * blockDim.x + threadIdx.x;
  if (t >= T_TOK) return;
#pragma unroll
  for (int k = 0; k < 2; k++) {
    int e = top_idx[t * 2 + k];
    int c = atomicAdd(&cursor[e], 1);
    int slot = offpad[e] + c;
    list_tok[slot] = t;
    list_gate[slot] = top_gate[t * 2 + k];
  }
}

// ---------------- GEMM ----------------
// A: bf16 [*,K] row-major. B1t/B2t: bf16 [N,K] (pre-transposed). 128x128 tile,
// BK=32, 4 waves (2x2), each wave 64x64 via 4x4 mfma_f32_16x16x32_bf16 frags.
// MODE 0: dual-B, epilogue silu(h1)*h2 -> bf16 C.   (ROUTED: A gathered via list)
// MODE 1: single-B, fp32 store to C.
// MODE 2: single-B, scatter atomicAdd(gate*v) into Obase rows list_tok[].
template <int MODE, bool ROUTED>
__global__ __launch_bounds__(256, 2) void gemm_bf16(
    const u16* __restrict__ Abase, const u16* __restrict__ B1base,
    const u16* __restrict__ B2base, void* __restrict__ Cbase,
    float* __restrict__ Obase, const int* __restrict__ list_tok,
    const float* __restrict__ list_gate, const int* __restrict__ counts,
    const int* __restrict__ offpad, int M, int N, int K) {
  constexpr bool DUAL = (MODE == 0);
  const int tid = threadIdx.x;
  const int lane = tid & 63;
  const int w = tid >> 6;
  const int wr = w >> 1, wc = w & 1;

  int cnt = M, base = 0, e = 0;
  if (ROUTED) {
    e = blockIdx.z;
    cnt = counts[e];
    base = offpad[e];
  }
  const int m0 = blockIdx.y * 128;
  const int n0 = blockIdx.x * 128;
  if (ROUTED && m0 >= cnt) return;

  const u16* A = Abase;
  const u16* B1 = B1base + (ROUTED ? (size_t)e * N * K : (size_t)0);
  const u16* B2 = DUAL ? (B2base + (ROUTED ? (size_t)e * N * K : (size_t)0)) : nullptr;
  if (ROUTED && MODE == 2) A += (size_t)base * K;

  __shared__ __align__(16) u16 ldsA[128 * 32];
  __shared__ __align__(16) u16 ldsB1[128 * 32];
  __shared__ __align__(16) u16 ldsB2[DUAL ? 128 * 32 : 64];

  const int rr0 = w * 16 + (lane >> 2);       // staging row (16 rows/wave/instr)
  const int gcol = (lane & 3) * 8;            // element offset within row

  size_t arow0, arow1;
  if (ROUTED && MODE == 0) {
    int r0 = min(m0 + rr0, cnt - 1);
    int r1 = min(m0 + 64 + rr0, cnt - 1);
    arow0 = (size_t)list_tok[base + r0];
    arow1 = (size_t)list_tok[base + r1];
  } else {
    arow0 = (size_t)(m0 + rr0);
    arow1 = (size_t)(m0 + 64 + rr0);
  }
  const u16* gA0 = A + arow0 * K + gcol;
  const u16* gA1 = A + arow1 * K + gcol;
  const u16* gB10 = B1 + (size_t)(n0 + rr0) * K + gcol;
  const u16* gB11 = B1 + (size_t)(n0 + 64 + rr0) * K + gcol;
  const u16* gB20 = DUAL ? B2 + (size_t)(n0 + rr0) * K + gcol : nullptr;
  const u16* gB21 = DUAL ? B2 + (size_t)(n0 + 64 + rr0) * K + gcol : nullptr;

  u16* lA0 = ldsA + (w * 64) * 8;             // wave-uniform LDS bases
  u16* lA1 = ldsA + (256 + w * 64) * 8;
  u16* lB10 = ldsB1 + (w * 64) * 8;
  u16* lB11 = ldsB1 + (256 + w * 64) * 8;
  u16* lB20 = ldsB2 + (w * 64) * 8;
  u16* lB21 = ldsB2 + (256 + w * 64) * 8;

  int aoff[4], boff[4];
#pragma unroll
  for (int i = 0; i < 4; i++) {
    aoff[i] = (wr * 64 + i * 16 + (lane & 15)) * 32 + (lane >> 4) * 8;
    boff[i] = (wc * 64 + i * 16 + (lane & 15)) * 32 + (lane >> 4) * 8;
  }

  f32x4 acc1[4][4];
  f32x4 acc2[DUAL ? 4 : 1][DUAL ? 4 : 1];
#pragma unroll
  for (int m = 0; m < 4; m++)
#pragma unroll
    for (int n = 0; n < 4; n++) {
      acc1[m][n] = (f32x4){0.f, 0.f, 0.f, 0.f};
      if constexpr (DUAL) acc2[m][n] = (f32x4){0.f, 0.f, 0.f, 0.f};
    }

  for (int k0 = 0; k0 < K; k0 += 32) {
    gload_lds16(gA0 + k0, lA0);
    gload_lds16(gA1 + k0, lA1);
    gload_lds16(gB10 + k0, lB10);
    gload_lds16(gB11 + k0, lB11);
    if constexpr (DUAL) {
      gload_lds16(gB20 + k0, lB20);
      gload_lds16(gB21 + k0, lB21);
    }
    __syncthreads();
    bf16x8 af[4], b1f[4];
#pragma unroll
    for (int i = 0; i < 4; i++) af[i] = *(const bf16x8*)(ldsA + aoff[i]);
#pragma unroll
    for (int i = 0; i < 4; i++) b1f[i] = *(const bf16x8*)(ldsB1 + boff[i]);
#pragma unroll
    for (int m = 0; m < 4; m++)
#pragma unroll
      for (int n = 0; n < 4; n++)
        acc1[m][n] = __builtin_amdgcn_mfma_f32_16x16x32_bf16(af[m], b1f[n], acc1[m][n], 0, 0, 0);
    if constexpr (DUAL) {
      bf16x8 b2f[4];
#pragma unroll
      for (int i = 0; i < 4; i++) b2f[i] = *(const bf16x8*)(ldsB2 + boff[i]);
#pragma unroll
      for (int m = 0; m < 4; m++)
#pragma unroll
        for (int n = 0; n < 4; n++)
          acc2[m][n] = __builtin_amdgcn_mfma_f32_16x16x32_bf16(af[m], b2f[n], acc2[m][n], 0, 0, 0);
    }
    __syncthreads();
  }

  const int crow = (lane >> 4) * 4;
  const int ccol = lane & 15;

  if constexpr (MODE == 0) {
    u16* C = (u16*)Cbase + (ROUTED ? (size_t)base * N : (size_t)0);
#pragma unroll
    for (int m = 0; m < 4; m++)
#pragma unroll
      for (int n = 0; n < 4; n++) {
        int col = n0 + wc * 64 + n * 16 + ccol;
#pragma unroll
        for (int j = 0; j < 4; j++) {
          int row = m0 + wr * 64 + m * 16 + crow + j;
          float h1 = acc1[m][n][j];
          float h2 = acc2[m][n][j];
          float sv = (h1 / (1.0f + __expf(-h1))) * h2;
          C[(size_t)row * N + col] = f2bf(sv);
        }
      }
  } else if constexpr (MODE == 1) {
    float* C = (float*)Cbase;
#pragma unroll
    for (int m = 0; m < 4; m++)
#pragma unroll
      for (int n = 0; n < 4; n++) {
        int col = n0 + wc * 64 + n * 16 + ccol;
#pragma unroll
        for (int j = 0; j < 4; j++) {
          int row = m0 + wr * 64 + m * 16 + crow + j;
          C[(size_t)row * N + col] = acc1[m][n][j];
        }
      }
  } else {
#pragma unroll
    for (int m = 0; m < 4; m++) {
      int rl[4], tk[4];
      float gt[4];
#pragma unroll
      for (int j = 0; j < 4; j++) {
        rl[j] = m0 + wr * 64 + m * 16 + crow + j;
        tk[j] = 0; gt[j] = 0.f;
        if (rl[j] < cnt) {
          tk[j] = list_tok[base + rl[j]];
          gt[j] = list_gate[base + rl[j]];
        }
      }
#pragma unroll
      for (int n = 0; n < 4; n++) {
        int col = n0 + wc * 64 + n * 16 + ccol;
#pragma unroll
        for (int j = 0; j < 4; j++)
          if (rl[j] < cnt)
            atomicAdd(&Obase[(size_t)tk[j] * N + col], gt[j] * acc1[m][n][j]);
      }
    }
  }
}

// ---------------- launch ----------------

extern "C" void kernel_launch(void* const* d_in, const int* in_sizes, int n_in,
                              void* d_out, int out_size, void* d_ws, size_t ws_size,
                              hipStream_t stream) {
  (void)in_sizes; (void)n_in; (void)out_size;
  const float* x    = (const float*)d_in[0];
  const float* rwt  = (const float*)d_in[1];
  const float* bias = (const float*)d_in[2];
  const float* sw1  = (const float*)d_in[3];
  const float* sw2  = (const float*)d_in[4];
  const float* sw3  = (const float*)d_in[5];
  const float* rw1  = (const float*)d_in[6];
  const float* rw2  = (const float*)d_in[7];
  const float* rw3  = (const float*)d_in[8];
  float* out = (float*)d_out;

  char* p = (char*)d_ws;
  size_t off = 0;
  auto take = [&](size_t bytes) -> void* {
    void* r = p + off;
    off += (bytes + 255) & ~(size_t)255;
    return r;
  };
  const int max_slots = T_TOK * 2 + NEXP * 128;  // 34816
  // act union buffer: shared-chunk activations (CHUNK_T x HDIM bf16 = 64 MB)
  // and routed activations (max_slots x RHDIM bf16 = 68 MB) used sequentially.
  const size_t act_bytes = (size_t)max_slots * RHDIM * 2;  // >= CHUNK_T*HDIM*2
  u16* xb      = (u16*)take((size_t)T_TOK * DDIM * 2);
  u16* sw1t    = (u16*)take((size_t)HDIM * DDIM * 2);
  u16* sw2t    = (u16*)take((size_t)HDIM * DDIM * 2);
  u16* sw3t    = (u16*)take((size_t)DDIM * HDIM * 2);
  u16* rw1t    = (u16*)take((size_t)NEXP * RHDIM * DDIM * 2);
  u16* rw2t    = (u16*)take((size_t)NEXP * RHDIM * DDIM * 2);
  u16* rw3t    = (u16*)take((size_t)NEXP * DDIM * RHDIM * 2);
  u16* act     = (u16*)take(act_bytes);
  int* top_idx = (int*)take((size_t)T_TOK * 2 * 4);
  float* top_gate = (float*)take((size_t)T_TOK * 2 * 4);
  int* counts  = (int*)take(64);
  int* cursor  = (int*)take(64);
  int* offpad  = (int*)take(64);
  int* list_tok = (int*)take((size_t)max_slots * 4);
  float* list_gate = (float*)take((size_t)max_slots * 4);

  if (off > ws_size) {
    // Workspace too small: report its size via the absmax channel and bail.
    ws_diag_kernel<<<1, 64, 0, stream>>>(out, (float)ws_size);
    return;
  }

  hipMemsetAsync(counts, 0, 64, stream);
  hipMemsetAsync(cursor, 0, 64, stream);

  cvt_bf16_kernel<<<4096, 256, 0, stream>>>(x, xb, T_TOK * DDIM / 4);
  dim3 tb(32, 8);
  transpose_cvt<<<dim3(HDIM / 32, DDIM / 32, 1), tb, 0, stream>>>(sw1, sw1t, DDIM, HDIM);
  transpose_cvt<<<dim3(HDIM / 32, DDIM / 32, 1), tb, 0, stream>>>(sw2, sw2t, DDIM, HDIM);
  transpose_cvt<<<dim3(DDIM / 32, HDIM / 32, 1), tb, 0, stream>>>(sw3, sw3t, HDIM, DDIM);
  transpose_cvt<<<dim3(RHDIM / 32, DDIM / 32, NEXP), tb, 0, stream>>>(rw1, rw1t, DDIM, RHDIM);
  transpose_cvt<<<dim3(RHDIM / 32, DDIM / 32, NEXP), tb, 0, stream>>>(rw2, rw2t, DDIM, RHDIM);
  transpose_cvt<<<dim3(DDIM / 32, RHDIM / 32, NEXP), tb, 0, stream>>>(rw3, rw3t, RHDIM, DDIM);

  router_kernel<<<T_TOK, 64, 0, stream>>>(x, rwt, bias, top_idx, top_gate, counts);
  offsets_kernel<<<1, 64, 0, stream>>>(counts, offpad);
  fill_kernel<<<T_TOK / 256, 256, 0, stream>>>(top_idx, top_gate, offpad, cursor,
                                               list_tok, list_gate);

  // shared expert in 2 token-chunks; act buffer reused per chunk
  for (int c = 0; c < 2; ++c) {
    const u16* xA = xb + (size_t)c * CHUNK_T * DDIM;
    float* outC = out + (size_t)c * CHUNK_T * DDIM;
    // up-proj (fused w1/w2 + SwiGLU) -> act bf16 [CHUNK_T, H]
    gemm_bf16<0, false><<<dim3(HDIM / 128, CHUNK_T / 128), 256, 0, stream>>>(
        xA, sw1t, sw2t, act, nullptr, nullptr, nullptr, nullptr, nullptr,
        CHUNK_T, HDIM, DDIM);
    // down-proj -> out fp32 chunk (initializes every element of the chunk)
    gemm_bf16<1, false><<<dim3(DDIM / 128, CHUNK_T / 128), 256, 0, stream>>>(
        act, sw3t, nullptr, outC, nullptr, nullptr, nullptr, nullptr, nullptr,
        CHUNK_T, DDIM, HDIM);
  }

  // routed up-proj (gathered rows, fused SwiGLU) -> act bf16 (reused buffer)
  gemm_bf16<0, true><<<dim3(RHDIM / 128, T_TOK / 128, NEXP), 256, 0, stream>>>(
      xb, rw1t, rw2t, act, nullptr, list_tok, list_gate, counts, offpad,
      T_TOK, RHDIM, DDIM);
  // routed down-proj + gate*scatter-add into out
  gemm_bf16<2, true><<<dim3(DDIM / 128, T_TOK / 128, NEXP), 256, 0, stream>>>(
      act, rw3t, nullptr, nullptr, out, list_tok, list_gate, counts, offpad,
      T_TOK, DDIM, RHDIM);
}

// Round 3
// 1534.901 us; speedup vs baseline: 1.1612x; 1.1612x over previous
//
#include <hip/hip_runtime.h>
#include <hip/hip_bf16.h>
#include <cstdint>

#define T_TOK 16384
#define DDIM 1024
#define HDIM 4096
#define RHDIM 1024
#define NEXP 16
#define CHUNK_T 8192
#define RT_TOK 64
#define RT_DC 128

typedef unsigned short u16;
typedef __attribute__((ext_vector_type(4))) float f32x4;
typedef __attribute__((ext_vector_type(8))) __bf16 bf16x8;

__device__ __forceinline__ u16 f2bf(float f) {
  uint32_t u = __builtin_bit_cast(uint32_t, f);
  u += 0x7FFFu + ((u >> 16) & 1u);
  return (u16)(u >> 16);
}

__device__ __forceinline__ void gload_lds16(const void* g, void* l) {
  __builtin_amdgcn_global_load_lds(
      (const __attribute__((address_space(1))) void*)g,
      (__attribute__((address_space(3))) void*)l, 16, 0, 0);
}

// ---------------- diagnostics ----------------

__global__ void ws_diag_kernel(float* __restrict__ out, float wssz) {
  if (threadIdx.x == 0 && blockIdx.x == 0) out[0] = wssz;
}

// ---------------- conversion kernels ----------------

__global__ void cvt_bf16_kernel(const float* __restrict__ in, u16* __restrict__ out, int n4) {
  for (int i = blockIdx.x * blockDim.x + threadIdx.x; i < n4; i += gridDim.x * blockDim.x) {
    float4 v = ((const float4*)in)[i];
    ushort4 o;
    o.x = f2bf(v.x); o.y = f2bf(v.y); o.z = f2bf(v.z); o.w = f2bf(v.w);
    ((ushort4*)out)[i] = o;
  }
}

// in: fp32 [R,C] (batch blockIdx.z), out: bf16 [C,R]
__global__ void transpose_cvt(const float* __restrict__ in, u16* __restrict__ out, int R, int C) {
  __shared__ float tile[32][33];
  const size_t bo = (size_t)blockIdx.z * R * C;
  in += bo; out += bo;
  const int c0 = blockIdx.x * 32, r0 = blockIdx.y * 32;
  const int tx = threadIdx.x, ty = threadIdx.y;  // 32 x 8
#pragma unroll
  for (int i = 0; i < 4; i++)
    tile[ty + 8 * i][tx] = in[(size_t)(r0 + ty + 8 * i) * C + c0 + tx];
  __syncthreads();
#pragma unroll
  for (int i = 0; i < 4; i++)
    out[(size_t)(c0 + ty + 8 * i) * R + r0 + tx] = f2bf(tile[tx][ty + 8 * i]);
}

// ---------------- routing ----------------
// LDS-tiled tall-skinny GEMM: block = 256 threads, 64 tokens.
// thread = (token = tid>>2, expert-quad = tid&3); fp32 throughout so the
// top-k selection matches the fp32 reference (no bf16 selection flips).

__global__ __launch_bounds__(256) void router_kernel(
    const float* __restrict__ x, const float* __restrict__ rw,
    const float* __restrict__ bias, int* __restrict__ top_idx,
    float* __restrict__ top_gate, int* __restrict__ counts) {
  __shared__ float xt[RT_TOK][RT_DC + 4];
  __shared__ float wt[RT_DC][NEXP];
  __shared__ float sc[RT_TOK][NEXP + 1];
  const int tid = threadIdx.x;
  const int t0 = blockIdx.x * RT_TOK;
  const int tok = tid >> 2;
  const int ep = tid & 3;
  float acc[4] = {0.f, 0.f, 0.f, 0.f};

  for (int dc = 0; dc < DDIM; dc += RT_DC) {
    // stage x tile [64][128] fp32, coalesced float4 (32 lanes cover one row)
#pragma unroll
    for (int j = 0; j < 8; j++) {
      const int r = (tid >> 5) + 8 * j;
      const int c4 = tid & 31;
      *(float4*)&xt[r][c4 * 4] =
          *(const float4*)(x + (size_t)(t0 + r) * DDIM + dc + c4 * 4);
    }
    // stage rw chunk [128][16] fp32 (contiguous rows)
#pragma unroll
    for (int j = 0; j < 2; j++) {
      const int idx = tid + j * 256;  // float4 index 0..511
      ((float4*)wt)[idx] = *(const float4*)(rw + (size_t)dc * NEXP + idx * 4);
    }
    __syncthreads();
#pragma unroll
    for (int d = 0; d < RT_DC; d++) {
      const float xv = xt[tok][d];
      const float4 w = *(const float4*)&wt[d][ep * 4];
      acc[0] += xv * w.x; acc[1] += xv * w.y;
      acc[2] += xv * w.z; acc[3] += xv * w.w;
    }
    __syncthreads();
  }
#pragma unroll
  for (int e = 0; e < 4; e++) sc[tok][ep * 4 + e] = acc[e];
  __syncthreads();

  if (tid < RT_TOK) {
    const int t = t0 + tid;
    float s[NEXP], sel[NEXP];
#pragma unroll
    for (int e = 0; e < NEXP; e++) {
      s[e] = 1.f / (1.f + expf(-sc[tid][e]));
      sel[e] = s[e] + bias[e];
    }
    int i1 = 0; float m1 = sel[0];
    for (int e = 1; e < NEXP; e++) if (sel[e] > m1) { m1 = sel[e]; i1 = e; }
    int i2 = -1; float m2 = -1e30f;
    for (int e = 0; e < NEXP; e++) if (e != i1 && sel[e] > m2) { m2 = sel[e]; i2 = e; }
    top_idx[t * 2] = i1; top_idx[t * 2 + 1] = i2;
    top_gate[t * 2] = s[i1]; top_gate[t * 2 + 1] = s[i2];
    atomicAdd(&counts[i1], 1);
    atomicAdd(&counts[i2], 1);
  }
}

__global__ void offsets_kernel(const int* __restrict__ counts, int* __restrict__ offpad) {
  if (threadIdx.x == 0 && blockIdx.x == 0) {
    int o = 0;
    for (int e = 0; e < NEXP; e++) { offpad[e] = o; o += (counts[e] + 127) & ~127; }
  }
}

__global__ void fill_kernel(const int* __restrict__ top_idx, const float* __restrict__ top_gate,
                            const int* __restrict__ offpad, int* __restrict__ cursor,
                            int* __restrict__ list_tok, float* __restrict__ list_gate) {
  int t = blockIdx.x * blockDim.x + threadIdx.x;
  if (t >= T_TOK) return;
#pragma unroll
  for (int k = 0; k < 2; k++) {
    int e = top_idx[t * 2 + k];
    int c = atomicAdd(&cursor[e], 1);
    int slot = offpad[e] + c;
    list_tok[slot] = t;
    list_gate[slot] = top_gate[t * 2 + k];
  }
}

// ---------------- GEMM ----------------
// A: bf16 [*,K] row-major. B1t/B2t: bf16 [N,K] (pre-transposed). 128x128 tile,
// BK=32, 4 waves (2x2), each wave 64x64 via 4x4 mfma_f32_16x16x32_bf16 frags.
// MODE 0: dual-B, epilogue silu(h1)*h2 -> bf16 C.   (ROUTED: A gathered via list)
// MODE 1: single-B, fp32 store to C.
// MODE 2: single-B, scatter atomicAdd(gate*v) into Obase rows list_tok[].
template <int MODE, bool ROUTED>
__global__ __launch_bounds__(256, 2) void gemm_bf16(
    const u16* __restrict__ Abase, const u16* __restrict__ B1base,
    const u16* __restrict__ B2base, void* __restrict__ Cbase,
    float* __restrict__ Obase, const int* __restrict__ list_tok,
    const float* __restrict__ list_gate, const int* __restrict__ counts,
    const int* __restrict__ offpad, int M, int N, int K) {
  constexpr bool DUAL = (MODE == 0);
  const int tid = threadIdx.x;
  const int lane = tid & 63;
  const int w = tid >> 6;
  const int wr = w >> 1, wc = w & 1;

  int cnt = M, base = 0, e = 0;
  if (ROUTED) {
    e = blockIdx.z;
    cnt = counts[e];
    base = offpad[e];
  }
  const int m0 = blockIdx.y * 128;
  const int n0 = blockIdx.x * 128;
  if (ROUTED && m0 >= cnt) return;

  const u16* A = Abase;
  const u16* B1 = B1base + (ROUTED ? (size_t)e * N * K : (size_t)0);
  const u16* B2 = DUAL ? (B2base + (ROUTED ? (size_t)e * N * K : (size_t)0)) : nullptr;
  if (ROUTED && MODE == 2) A += (size_t)base * K;

  __shared__ __align__(16) u16 ldsA[128 * 32];
  __shared__ __align__(16) u16 ldsB1[128 * 32];
  __shared__ __align__(16) u16 ldsB2[DUAL ? 128 * 32 : 64];

  const int rr0 = w * 16 + (lane >> 2);       // staging row (16 rows/wave/instr)
  const int gcol = (lane & 3) * 8;            // element offset within row

  size_t arow0, arow1;
  if (ROUTED && MODE == 0) {
    int r0 = min(m0 + rr0, cnt - 1);
    int r1 = min(m0 + 64 + rr0, cnt - 1);
    arow0 = (size_t)list_tok[base + r0];
    arow1 = (size_t)list_tok[base + r1];
  } else {
    arow0 = (size_t)(m0 + rr0);
    arow1 = (size_t)(m0 + 64 + rr0);
  }
  const u16* gA0 = A + arow0 * K + gcol;
  const u16* gA1 = A + arow1 * K + gcol;
  const u16* gB10 = B1 + (size_t)(n0 + rr0) * K + gcol;
  const u16* gB11 = B1 + (size_t)(n0 + 64 + rr0) * K + gcol;
  const u16* gB20 = DUAL ? B2 + (size_t)(n0 + rr0) * K + gcol : nullptr;
  const u16* gB21 = DUAL ? B2 + (size_t)(n0 + 64 + rr0) * K + gcol : nullptr;

  u16* lA0 = ldsA + (w * 64) * 8;             // wave-uniform LDS bases
  u16* lA1 = ldsA + (256 + w * 64) * 8;
  u16* lB10 = ldsB1 + (w * 64) * 8;
  u16* lB11 = ldsB1 + (256 + w * 64) * 8;
  u16* lB20 = ldsB2 + (w * 64) * 8;
  u16* lB21 = ldsB2 + (256 + w * 64) * 8;

  int aoff[4], boff[4];
#pragma unroll
  for (int i = 0; i < 4; i++) {
    aoff[i] = (wr * 64 + i * 16 + (lane & 15)) * 32 + (lane >> 4) * 8;
    boff[i] = (wc * 64 + i * 16 + (lane & 15)) * 32 + (lane >> 4) * 8;
  }

  f32x4 acc1[4][4];
  f32x4 acc2[DUAL ? 4 : 1][DUAL ? 4 : 1];
#pragma unroll
  for (int m = 0; m < 4; m++)
#pragma unroll
    for (int n = 0; n < 4; n++) {
      acc1[m][n] = (f32x4){0.f, 0.f, 0.f, 0.f};
      if constexpr (DUAL) acc2[m][n] = (f32x4){0.f, 0.f, 0.f, 0.f};
    }

  for (int k0 = 0; k0 < K; k0 += 32) {
    gload_lds16(gA0 + k0, lA0);
    gload_lds16(gA1 + k0, lA1);
    gload_lds16(gB10 + k0, lB10);
    gload_lds16(gB11 + k0, lB11);
    if constexpr (DUAL) {
      gload_lds16(gB20 + k0, lB20);
      gload_lds16(gB21 + k0, lB21);
    }
    __syncthreads();
    bf16x8 af[4], b1f[4];
#pragma unroll
    for (int i = 0; i < 4; i++) af[i] = *(const bf16x8*)(ldsA + aoff[i]);
#pragma unroll
    for (int i = 0; i < 4; i++) b1f[i] = *(const bf16x8*)(ldsB1 + boff[i]);
#pragma unroll
    for (int m = 0; m < 4; m++)
#pragma unroll
      for (int n = 0; n < 4; n++)
        acc1[m][n] = __builtin_amdgcn_mfma_f32_16x16x32_bf16(af[m], b1f[n], acc1[m][n], 0, 0, 0);
    if constexpr (DUAL) {
      bf16x8 b2f[4];
#pragma unroll
      for (int i = 0; i < 4; i++) b2f[i] = *(const bf16x8*)(ldsB2 + boff[i]);
#pragma unroll
      for (int m = 0; m < 4; m++)
#pragma unroll
        for (int n = 0; n < 4; n++)
          acc2[m][n] = __builtin_amdgcn_mfma_f32_16x16x32_bf16(af[m], b2f[n], acc2[m][n], 0, 0, 0);
    }
    __syncthreads();
  }

  const int crow = (lane >> 4) * 4;
  const int ccol = lane & 15;

  if constexpr (MODE == 0) {
    u16* C = (u16*)Cbase + (ROUTED ? (size_t)base * N : (size_t)0);
#pragma unroll
    for (int m = 0; m < 4; m++)
#pragma unroll
      for (int n = 0; n < 4; n++) {
        int col = n0 + wc * 64 + n * 16 + ccol;
#pragma unroll
        for (int j = 0; j < 4; j++) {
          int row = m0 + wr * 64 + m * 16 + crow + j;
          float h1 = acc1[m][n][j];
          float h2 = acc2[m][n][j];
          float sv = (h1 / (1.0f + __expf(-h1))) * h2;
          C[(size_t)row * N + col] = f2bf(sv);
        }
      }
  } else if constexpr (MODE == 1) {
    float* C = (float*)Cbase;
#pragma unroll
    for (int m = 0; m < 4; m++)
#pragma unroll
      for (int n = 0; n < 4; n++) {
        int col = n0 + wc * 64 + n * 16 + ccol;
#pragma unroll
        for (int j = 0; j < 4; j++) {
          int row = m0 + wr * 64 + m * 16 + crow + j;
          C[(size_t)row * N + col] = acc1[m][n][j];
        }
      }
  } else {
#pragma unroll
    for (int m = 0; m < 4; m++) {
      int rl[4], tk[4];
      float gt[4];
#pragma unroll
      for (int j = 0; j < 4; j++) {
        rl[j] = m0 + wr * 64 + m * 16 + crow + j;
        tk[j] = 0; gt[j] = 0.f;
        if (rl[j] < cnt) {
          tk[j] = list_tok[base + rl[j]];
          gt[j] = list_gate[base + rl[j]];
        }
      }
#pragma unroll
      for (int n = 0; n < 4; n++) {
        int col = n0 + wc * 64 + n * 16 + ccol;
#pragma unroll
        for (int j = 0; j < 4; j++)
          if (rl[j] < cnt)
            atomicAdd(&Obase[(size_t)tk[j] * N + col], gt[j] * acc1[m][n][j]);
      }
    }
  }
}

// ---------------- launch ----------------

extern "C" void kernel_launch(void* const* d_in, const int* in_sizes, int n_in,
                              void* d_out, int out_size, void* d_ws, size_t ws_size,
                              hipStream_t stream) {
  (void)in_sizes; (void)n_in; (void)out_size;
  const float* x    = (const float*)d_in[0];
  const float* rwt  = (const float*)d_in[1];
  const float* bias = (const float*)d_in[2];
  const float* sw1  = (const float*)d_in[3];
  const float* sw2  = (const float*)d_in[4];
  const float* sw3  = (const float*)d_in[5];
  const float* rw1  = (const float*)d_in[6];
  const float* rw2  = (const float*)d_in[7];
  const float* rw3  = (const float*)d_in[8];
  float* out = (float*)d_out;

  char* p = (char*)d_ws;
  size_t off = 0;
  auto take = [&](size_t bytes) -> void* {
    void* r = p + off;
    off += (bytes + 255) & ~(size_t)255;
    return r;
  };
  const int max_slots = T_TOK * 2 + NEXP * 128;  // 34816
  // act union buffer: shared-chunk activations (CHUNK_T x HDIM bf16 = 64 MB)
  // and routed activations (max_slots x RHDIM bf16 = 68 MB) used sequentially.
  const size_t act_bytes = (size_t)max_slots * RHDIM * 2;  // >= CHUNK_T*HDIM*2
  u16* xb      = (u16*)take((size_t)T_TOK * DDIM * 2);
  u16* sw1t    = (u16*)take((size_t)HDIM * DDIM * 2);
  u16* sw2t    = (u16*)take((size_t)HDIM * DDIM * 2);
  u16* sw3t    = (u16*)take((size_t)DDIM * HDIM * 2);
  u16* rw1t    = (u16*)take((size_t)NEXP * RHDIM * DDIM * 2);
  u16* rw2t    = (u16*)take((size_t)NEXP * RHDIM * DDIM * 2);
  u16* rw3t    = (u16*)take((size_t)NEXP * DDIM * RHDIM * 2);
  u16* act     = (u16*)take(act_bytes);
  int* top_idx = (int*)take((size_t)T_TOK * 2 * 4);
  float* top_gate = (float*)take((size_t)T_TOK * 2 * 4);
  int* counts  = (int*)take(64);
  int* cursor  = (int*)take(64);
  int* offpad  = (int*)take(64);
  int* list_tok = (int*)take((size_t)max_slots * 4);
  float* list_gate = (float*)take((size_t)max_slots * 4);

  if (off > ws_size) {
    // Workspace too small: report its size via the absmax channel and bail.
    ws_diag_kernel<<<1, 64, 0, stream>>>(out, (float)ws_size);
    return;
  }

  hipMemsetAsync(counts, 0, 64, stream);
  hipMemsetAsync(cursor, 0, 64, stream);

  cvt_bf16_kernel<<<4096, 256, 0, stream>>>(x, xb, T_TOK * DDIM / 4);
  dim3 tb(32, 8);
  transpose_cvt<<<dim3(HDIM / 32, DDIM / 32, 1), tb, 0, stream>>>(sw1, sw1t, DDIM, HDIM);
  transpose_cvt<<<dim3(HDIM / 32, DDIM / 32, 1), tb, 0, stream>>>(sw2, sw2t, DDIM, HDIM);
  transpose_cvt<<<dim3(DDIM / 32, HDIM / 32, 1), tb, 0, stream>>>(sw3, sw3t, HDIM, DDIM);
  transpose_cvt<<<dim3(RHDIM / 32, DDIM / 32, NEXP), tb, 0, stream>>>(rw1, rw1t, DDIM, RHDIM);
  transpose_cvt<<<dim3(RHDIM / 32, DDIM / 32, NEXP), tb, 0, stream>>>(rw2, rw2t, DDIM, RHDIM);
  transpose_cvt<<<dim3(DDIM / 32, RHDIM / 32, NEXP), tb, 0, stream>>>(rw3, rw3t, RHDIM, DDIM);

  router_kernel<<<T_TOK / RT_TOK, 256, 0, stream>>>(x, rwt, bias, top_idx, top_gate, counts);
  offsets_kernel<<<1, 64, 0, stream>>>(counts, offpad);
  fill_kernel<<<T_TOK / 256, 256, 0, stream>>>(top_idx, top_gate, offpad, cursor,
                                               list_tok, list_gate);

  // shared expert in 2 token-chunks; act buffer reused per chunk
  for (int c = 0; c < 2; ++c) {
    const u16* xA = xb + (size_t)c * CHUNK_T * DDIM;
    float* outC = out + (size_t)c * CHUNK_T * DDIM;
    // up-proj (fused w1/w2 + SwiGLU) -> act bf16 [CHUNK_T, H]
    gemm_bf16<0, false><<<dim3(HDIM / 128, CHUNK_T / 128), 256, 0, stream>>>(
        xA, sw1t, sw2t, act, nullptr, nullptr, nullptr, nullptr, nullptr,
        CHUNK_T, HDIM, DDIM);
    // down-proj -> out fp32 chunk (initializes every element of the chunk)
    gemm_bf16<1, false><<<dim3(DDIM / 128, CHUNK_T / 128), 256, 0, stream>>>(
        act, sw3t, nullptr, outC, nullptr, nullptr, nullptr, nullptr, nullptr,
        CHUNK_T, DDIM, HDIM);
  }

  // routed up-proj (gathered rows, fused SwiGLU) -> act bf16 (reused buffer)
  gemm_bf16<0, true><<<dim3(RHDIM / 128, T_TOK / 128, NEXP), 256, 0, stream>>>(
      xb, rw1t, rw2t, act, nullptr, list_tok, list_gate, counts, offpad,
      T_TOK, RHDIM, DDIM);
  // routed down-proj + gate*scatter-add into out
  gemm_bf16<2, true><<<dim3(DDIM / 128, T_TOK / 128, NEXP), 256, 0, stream>>>(
      act, rw3t, nullptr, nullptr, out, list_tok, list_gate, counts, offpad,
      T_TOK, DDIM, RHDIM);
}